// Round 2
// baseline (121.231 us; speedup 1.0000x reference)
//
#include <hip/hip_runtime.h>
#include <stdint.h>

typedef __attribute__((ext_vector_type(8))) short short8;
typedef __attribute__((ext_vector_type(4))) float f32x4;
typedef unsigned short ushort_t;

// fp32 -> bf16 round-to-nearest-even
__device__ __forceinline__ ushort_t f2bf(float f) {
  uint32_t u = __float_as_uint(f);
  u += 0x7fffu + ((u >> 16) & 1u);
  return (ushort_t)(u >> 16);
}

__device__ __forceinline__ uint2 pack4(float4 v) {
  return make_uint2((uint32_t)f2bf(v.x) | ((uint32_t)f2bf(v.y) << 16),
                    (uint32_t)f2bf(v.z) | ((uint32_t)f2bf(v.w) << 16));
}

// async global->LDS, 16B per lane; LDS dest = wave-uniform base + lane*16
__device__ __forceinline__ void load_lds16(const ushort_t* g, ushort_t* l) {
  __builtin_amdgcn_global_load_lds(
      (const __attribute__((address_space(1))) uint32_t*)g,
      (__attribute__((address_space(3))) uint32_t*)l, 16, 0, 0);
}

__device__ __forceinline__ void wait_loads(int rem) {
  if (rem >= 6)
    asm volatile("s_waitcnt vmcnt(6) lgkmcnt(0)" ::: "memory");
  else if (rem >= 3)
    asm volatile("s_waitcnt vmcnt(3) lgkmcnt(0)" ::: "memory");
  else
    asm volatile("s_waitcnt vmcnt(0) lgkmcnt(0)" ::: "memory");
}

// --- K1: fused front --------------------------------------------------------
// blocks 0..511   (G): Gt_u[b][o][m] = sum_i W[o,i]*H[b,m,i] + bias[o]
//                      W,H read fp32 directly (no precomverted copies).
// blocks 512..1535(P): dis[row] = rsqrt(rowsum(A)+1+eps)   (16 rows/block)
// G and P are independent -> BW pass overlaps compute pass.
__global__ __launch_bounds__(256) void k_front(
    const float4* __restrict__ A4,   // [32*512][128] fp32 rows
    const float4* __restrict__ H4,   // [32*512][64]  fp32 rows
    const float4* __restrict__ W4,   // [256][64]     fp32 rows
    const float* __restrict__ bias,  // [256]
    ushort_t* __restrict__ Gt,       // [32][256][512] bf16
    float* __restrict__ dis) {       // [32*512]
  __shared__ ushort_t Ws[64 * 256];    // whole W o-tile, bf16, 32 KB
  __shared__ ushort_t Bs[2][128 * 32]; // H k-step tiles, bf16, 2 x 8 KB
  const int bid = blockIdx.x, tid = threadIdx.x;

  if (bid >= 512) {  // ---- P: rowsum -> dis ----
    const int pidx = bid - 512;
    const int lane = tid & 63, wv = tid >> 6;
#pragma unroll
    for (int rr = 0; rr < 4; ++rr) {
      const int row = pidx * 16 + rr * 4 + wv;  // b*512+n
      const float4* src = A4 + (size_t)row * 128;
      float s = 0.0f;
#pragma unroll
      for (int i = 0; i < 2; ++i) {
        float4 v = src[i * 64 + lane];
        s += (v.x + v.y) + (v.z + v.w);
      }
#pragma unroll
      for (int off = 32; off > 0; off >>= 1) s += __shfl_down(s, off, 64);
      if (lane == 0) dis[row] = rsqrtf(s + 1.0f + 1e-8f);  // +1 self-loop
    }
    return;
  }

  // ---- G: GEMM, o-tile 64 x m-tile 128, K=256 (8 steps of 32) ----
  const int yo = bid >> 7;    // o-tile 0..3
  const int rb = bid & 127;
  const int batch = rb >> 2;  // 0..31
  const int xm = rb & 3;      // m-tile 0..3
  const int ot0 = yo * 64, mt0 = xm * 128;
  const int lane = tid & 63, wv = tid >> 6;
  const int wo = wv & 1;    // o half (2 x 32)
  const int wmh = wv >> 1;  // m half (2 x 64)
  const int lr = lane & 15, q = lane >> 4;
  const float4* Hb4 = H4 + (size_t)batch * 512 * 64;

  f32x4 acc[2][4];
#pragma unroll
  for (int i = 0; i < 2; ++i)
#pragma unroll
    for (int j = 0; j < 4; ++j) acc[i][j] = {0.f, 0.f, 0.f, 0.f};

  // H staging lane map: 8 lanes x float4 per row segment
  const int hr = tid >> 3, hc = tid & 7;
  float4 hs[2][4];
  auto loadH = [&](int step, float4* hv) {
#pragma unroll
    for (int c = 0; c < 4; ++c)
      hv[c] = Hb4[(size_t)(mt0 + hr + 32 * c) * 64 + step * 8 + hc];
  };
  // store slot s holds data chunk s ^ ((row>>1)&3)  (16B slots, matches rdoff)
  auto stageH = [&](const float4* hv, int p) {
    const int d = hc >> 1, sub = hc & 1;
#pragma unroll
    for (int c = 0; c < 4; ++c) {
      const int r = hr + 32 * c;
      *(uint2*)&Bs[p][r * 32 + ((d ^ ((r >> 1) & 3)) << 3) + (sub << 2)] =
          pack4(hv[c]);
    }
  };

  loadH(0, hs[0]);
  loadH(1, hs[1]);
  // W o-tile fp32 -> bf16 LDS, 16B-slot XOR swizzle by (o&7) (2-way banks)
#pragma unroll
  for (int i = 0; i < 16; ++i) {
    const int e4 = i * 256 + tid;
    const int o = e4 >> 6, k = (e4 & 63) * 4;
    *(uint2*)&Ws[o * 256 + (k ^ ((o & 7) << 3))] =
        pack4(W4[(size_t)ot0 * 64 + e4]);
  }
  asm volatile("s_waitcnt vmcnt(4)" ::: "memory");  // hs[0] landed (W drained)
  stageH(hs[0], 0);
  __syncthreads();  // Ws + Bs[0] visible

  auto compute = [&](int p, int it) {
    short8 af[2], bfr[4];
#pragma unroll
    for (int mt = 0; mt < 2; ++mt) {
      const int ro = wo * 32 + mt * 16 + lr;
      af[mt] = *(const short8*)&Ws[ro * 256 +
                                   ((it * 32 + q * 8) ^ ((ro & 7) << 3))];
    }
    const int rdoff = (q ^ ((lane >> 1) & 3)) * 8;
#pragma unroll
    for (int nt = 0; nt < 4; ++nt)
      bfr[nt] = *(const short8*)&Bs[p][(wmh * 64 + nt * 16 + lr) * 32 + rdoff];
#pragma unroll
    for (int mt = 0; mt < 2; ++mt)
#pragma unroll
      for (int nt = 0; nt < 4; ++nt)
        acc[mt][nt] = __builtin_amdgcn_mfma_f32_16x16x32_bf16(
            af[mt], bfr[nt], acc[mt][nt], 0, 0, 0);
  };

#pragma unroll
  for (int it = 0; it < 8; ++it) {
    if (it + 2 < 8) loadH(it + 2, hs[it & 1]);  // into set just retired
    compute(it & 1, it);
    if (it + 1 < 8) {
      if (it + 2 < 8)
        asm volatile("s_waitcnt vmcnt(4)" ::: "memory");  // set (it+1) landed
      else
        asm volatile("s_waitcnt vmcnt(0)" ::: "memory");
      stageH(hs[(it + 1) & 1], (it + 1) & 1);
    }
    __syncthreads();
  }

  // epilogue: Gt_u = acc + bias (bf16), no dis
#pragma unroll
  for (int mt = 0; mt < 2; ++mt) {
    const int ob = ot0 + wo * 32 + mt * 16 + q * 4;
    float bs4[4];
#pragma unroll
    for (int r = 0; r < 4; ++r) bs4[r] = bias[ob + r];
#pragma unroll
    for (int nt = 0; nt < 4; ++nt) {
      const int m = mt0 + wmh * 64 + nt * 16 + lr;
      ushort_t* dstp = Gt + ((size_t)batch * 256 + ob) * 512 + m;
#pragma unroll
      for (int r = 0; r < 4; ++r)
        dstp[(size_t)r * 512] = f2bf(acc[mt][nt][r] + bs4[r]);
    }
  }
}

// --- K2: Abf[b][n][m] = bf16( dis_n * (A+I)[n,m] * dis_m ) ------------------
// A re-read is L3-hot (k_front's rowsum pass just streamed it).
__global__ __launch_bounds__(256) void k_anorm(
    const float4* __restrict__ A4, const float* __restrict__ dis,
    ushort_t* __restrict__ Abf) {
  const int i = blockIdx.x * 256 + threadIdx.x;  // float4 idx (2,097,152)
  const int row = i >> 7;                        // b*512+n
  const int n = row & 511;
  const int b = row >> 9;
  const int c0 = (i & 127) * 4;  // m0
  float4 v = A4[i];
  v.x += (float)(c0 == n);
  v.y += (float)(c0 + 1 == n);
  v.z += (float)(c0 + 2 == n);
  v.w += (float)(c0 + 3 == n);
  const float dn = dis[row];
  const float4 dm = ((const float4*)dis)[(b << 7) + (i & 127)];
  v.x *= dn * dm.x;
  v.y *= dn * dm.y;
  v.z *= dn * dm.z;
  v.w *= dn * dm.w;
  ((uint2*)Abf)[i] = pack4(v);
}

// --- K3: out[b][n][o] = relu( (Anorm @ Gt_u)[n,o] * mask[b,n] ) -------------
// tile 128(n) x 64(o), K=512; 4-buffer, prefetch-depth-3, counted-vmcnt loop.
__global__ __launch_bounds__(256) void k_back(
    const ushort_t* __restrict__ Abf,  // [32][512][512] Anorm bf16
    const ushort_t* __restrict__ Gt,   // [32][256][512] bf16
    const float* __restrict__ mask,    // [32*512]
    float* __restrict__ out) {         // [32][512][256]
  __shared__ ushort_t As[4][128 * 32];
  __shared__ ushort_t Bs[4][64 * 32];
  const int bid = blockIdx.x;
  const int yo = bid >> 7;
  const int rb = bid & 127;
  const int batch = rb >> 2;
  const int xn = rb & 3;
  const int nt0 = xn * 128, ot0 = yo * 64;
  const int tid = threadIdx.x, lane = tid & 63, wv = tid >> 6;
  const int wnh = wv & 1;
  const int woh = wv >> 1;
  const int lr = lane & 15, q = lane >> 4;
  const int rstage = lane >> 2;
  const int koff = ((lane & 3) ^ ((lane >> 3) & 3)) * 8;
  const int rdoff = (q ^ ((lane >> 1) & 3)) * 8;
  const ushort_t* Ab = Abf + (size_t)batch * 512 * 512;
  const ushort_t* Gb = Gt + (size_t)batch * 256 * 512;

  f32x4 acc[4][2];
#pragma unroll
  for (int i = 0; i < 4; ++i)
#pragma unroll
    for (int j = 0; j < 2; ++j) acc[i][j] = {0.f, 0.f, 0.f, 0.f};

  auto stage = [&](int k0, int p) {
#pragma unroll
    for (int j = 0; j < 2; ++j) {
      const int c = wv * 2 + j;
      load_lds16(Ab + (size_t)(nt0 + c * 16 + rstage) * 512 + k0 + koff,
                 &As[p][c * 512]);
    }
    load_lds16(Gb + (size_t)(ot0 + wv * 16 + rstage) * 512 + k0 + koff,
               &Bs[p][wv * 512]);
  };
  auto compute = [&](int p) {
    short8 af[4], bfr[2];
#pragma unroll
    for (int mt = 0; mt < 4; ++mt)
      af[mt] = *(const short8*)&As[p][(wnh * 64 + mt * 16 + lr) * 32 + rdoff];
#pragma unroll
    for (int nt = 0; nt < 2; ++nt)
      bfr[nt] = *(const short8*)&Bs[p][(woh * 32 + nt * 16 + lr) * 32 + rdoff];
#pragma unroll
    for (int mt = 0; mt < 4; ++mt)
#pragma unroll
      for (int nt = 0; nt < 2; ++nt)
        acc[mt][nt] = __builtin_amdgcn_mfma_f32_16x16x32_bf16(
            af[mt], bfr[nt], acc[mt][nt], 0, 0, 0);
  };

  stage(0, 0);
  asm volatile("" ::: "memory");
  stage(32, 1);
  asm volatile("" ::: "memory");
  stage(64, 2);
#pragma unroll
  for (int it = 0; it < 16; ++it) {
    wait_loads(3 * (15 - it));
    __builtin_amdgcn_s_barrier();
    if (it + 3 < 16) stage((it + 3) * 32, (it + 3) & 3);
    compute(it & 3);
  }

#pragma unroll
  for (int mt = 0; mt < 4; ++mt) {
    const int nb = nt0 + wnh * 64 + mt * 16 + q * 4;
    float sc[4];
#pragma unroll
    for (int r = 0; r < 4; ++r) sc[r] = mask[batch * 512 + nb + r];
#pragma unroll
    for (int nt = 0; nt < 2; ++nt) {
      const int o = ot0 + woh * 32 + nt * 16 + lr;
      float* dstp = out + ((size_t)(batch * 512 + nb)) * 256 + o;
#pragma unroll
      for (int r = 0; r < 4; ++r) {
        float v = acc[mt][nt][r] * sc[r];
        dstp[(size_t)r * 256] = v > 0.0f ? v : 0.0f;
      }
    }
  }
}

extern "C" void kernel_launch(void* const* d_in, const int* in_sizes, int n_in,
                              void* d_out, int out_size, void* d_ws,
                              size_t ws_size, hipStream_t stream) {
  const float* H = (const float*)d_in[0];     // [32][512][256]
  const float* A = (const float*)d_in[1];     // [32][512][512]
  const float* mask = (const float*)d_in[2];  // [32][512]
  const float* W = (const float*)d_in[3];     // [256][256]
  const float* b = (const float*)d_in[4];     // [256]
  float* out = (float*)d_out;                 // [32][512][256]

  char* ws = (char*)d_ws;
  ushort_t* Abf = (ushort_t*)ws;                         // 16 MiB (Anorm)
  ushort_t* Gt = (ushort_t*)(ws + 16777216);             // 8 MiB  (Gt_u)
  float* dis = (float*)(ws + 16777216 + 8388608);        // 64 KiB

  // 1) fused: {Gt_u = W@H^T + b  (fp32 inputs direct)} || {rowsum(A) -> dis}
  k_front<<<1536, 256, 0, stream>>>((const float4*)A, (const float4*)H,
                                    (const float4*)W, b, Gt, dis);
  // 2) Abf = bf16(dis_n * (A+I) * dis_m)      (A re-read from L3)
  k_anorm<<<8192, 256, 0, stream>>>((const float4*)A, dis, Abf);
  // 3) out = relu(mask * (Anorm @ Gt_u))
  k_back<<<512, 256, 0, stream>>>(Abf, Gt, mask, out);
}

// Round 3
// 116.283 us; speedup vs baseline: 1.0425x; 1.0425x over previous
//
#include <hip/hip_runtime.h>
#include <stdint.h>

typedef __attribute__((ext_vector_type(8))) short short8;
typedef __attribute__((ext_vector_type(4))) float f32x4;
typedef unsigned short ushort_t;

// fp32 -> bf16 round-to-nearest-even
__device__ __forceinline__ ushort_t f2bf(float f) {
  uint32_t u = __float_as_uint(f);
  u += 0x7fffu + ((u >> 16) & 1u);
  return (ushort_t)(u >> 16);
}

__device__ __forceinline__ uint2 pack4(float4 v) {
  return make_uint2((uint32_t)f2bf(v.x) | ((uint32_t)f2bf(v.y) << 16),
                    (uint32_t)f2bf(v.z) | ((uint32_t)f2bf(v.w) << 16));
}

// async global->LDS, 16B per lane; LDS dest = wave-uniform base + lane*16
__device__ __forceinline__ void load_lds16(const ushort_t* g, ushort_t* l) {
  __builtin_amdgcn_global_load_lds(
      (const __attribute__((address_space(1))) uint32_t*)g,
      (__attribute__((address_space(3))) uint32_t*)l, 16, 0, 0);
}

// --- K1: prep ---------------------------------------------------------------
// per A row: deg -> dis, write (A+I) as bf16    (one wave per row, 4/block)
// (H/W conversions removed: k_gemm_gt reads them fp32 directly)
__global__ __launch_bounds__(256) void k_prep(
    const float4* __restrict__ A4, ushort_t* __restrict__ Abf,
    float* __restrict__ dis) {
  const int tid = threadIdx.x;
  const int row = blockIdx.x * 4 + (tid >> 6);  // b*512 + n
  const int lane = tid & 63;
  const int n = row & 511;
  const float4* src = A4 + (size_t)row * 128;
  uint2* dst = (uint2*)(Abf + (size_t)row * 512);
  float s = 0.0f;
#pragma unroll
  for (int i = 0; i < 2; ++i) {
    const int idx = i * 64 + lane;
    float4 v = src[idx];
    const int c0 = idx * 4;
    v.x += (float)(c0 == n);  // fold identity into the bf16 copy
    v.y += (float)(c0 + 1 == n);
    v.z += (float)(c0 + 2 == n);
    v.w += (float)(c0 + 3 == n);
    s += (v.x + v.y) + (v.z + v.w);
    dst[idx] = pack4(v);
  }
#pragma unroll
  for (int off = 32; off > 0; off >>= 1) s += __shfl_down(s, off, 64);
  if (lane == 0) dis[row] = rsqrtf(s + 1e-8f);
}

// --- K2: Gt[b][o][m] = (sum_i W[o,i]*H[b,m,i] + bias[o]) * dis[b,m] ---------
// o-tile 64 x m-tile 128, K=256 (8 steps of 32). W,H read fp32 directly:
// whole W o-tile converted once into 32 KB LDS; H reg-staged fp32->bf16,
// 2-deep double buffer. XOR 16B-slot swizzle on both LDS tiles (2-way banks).
// grid 512, bid = yo*128 + batch*4 + xm
__global__ __launch_bounds__(256) void k_gemm_gt(
    const float4* __restrict__ H4,   // [32*512][64]  fp32 rows
    const float4* __restrict__ W4,   // [256][64]     fp32 rows
    const float* __restrict__ bias,  // [256]
    const float* __restrict__ dis,   // [32*512]
    ushort_t* __restrict__ Gt) {     // [32][256][512] bf16
  __shared__ ushort_t Ws[64 * 256];     // whole W o-tile, bf16, 32 KB
  __shared__ ushort_t Bs[2][128 * 32];  // H k-step tiles, bf16, 2 x 8 KB
  const int bid = blockIdx.x, tid = threadIdx.x;
  const int yo = bid >> 7;    // o-tile 0..3
  const int rb = bid & 127;
  const int batch = rb >> 2;  // 0..31
  const int xm = rb & 3;      // m-tile 0..3
  const int ot0 = yo * 64, mt0 = xm * 128;
  const int lane = tid & 63, wv = tid >> 6;
  const int wo = wv & 1;    // o half (2 x 32)
  const int wmh = wv >> 1;  // m half (2 x 64)
  const int lr = lane & 15, q = lane >> 4;
  const float4* Hb4 = H4 + (size_t)batch * 512 * 64;

  f32x4 acc[2][4];
#pragma unroll
  for (int i = 0; i < 2; ++i)
#pragma unroll
    for (int j = 0; j < 4; ++j) acc[i][j] = {0.f, 0.f, 0.f, 0.f};

  // H staging lane map: 8 lanes x float4 per row segment
  const int hr = tid >> 3, hc = tid & 7;
  float4 hs[2][4];
  auto loadH = [&](int step, float4* hv) {
#pragma unroll
    for (int c = 0; c < 4; ++c)
      hv[c] = Hb4[(size_t)(mt0 + hr + 32 * c) * 64 + step * 8 + hc];
  };
  // store slot s holds data chunk s ^ ((row>>1)&3)  (16B slots, matches rdoff)
  auto stageH = [&](const float4* hv, int p) {
    const int d = hc >> 1, sub = hc & 1;
#pragma unroll
    for (int c = 0; c < 4; ++c) {
      const int r = hr + 32 * c;
      *(uint2*)&Bs[p][r * 32 + ((d ^ ((r >> 1) & 3)) << 3) + (sub << 2)] =
          pack4(hv[c]);
    }
  };

  loadH(0, hs[0]);
  loadH(1, hs[1]);
  // W o-tile fp32 -> bf16 LDS, 16B-slot XOR swizzle by (o&7) (2-way banks)
#pragma unroll
  for (int i = 0; i < 16; ++i) {
    const int e4 = i * 256 + tid;
    const int o = e4 >> 6, k = (e4 & 63) * 4;
    *(uint2*)&Ws[o * 256 + (k ^ ((o & 7) << 3))] =
        pack4(W4[(size_t)ot0 * 64 + e4]);
  }
  asm volatile("s_waitcnt vmcnt(4)" ::: "memory");  // hs[0] landed (W drained)
  stageH(hs[0], 0);
  __syncthreads();  // Ws + Bs[0] visible

  auto compute = [&](int p, int it) {
    short8 af[2], bfr[4];
#pragma unroll
    for (int mt = 0; mt < 2; ++mt) {
      const int ro = wo * 32 + mt * 16 + lr;
      af[mt] = *(const short8*)&Ws[ro * 256 +
                                   ((it * 32 + q * 8) ^ ((ro & 7) << 3))];
    }
    const int rdoff = (q ^ ((lane >> 1) & 3)) * 8;
#pragma unroll
    for (int nt = 0; nt < 4; ++nt)
      bfr[nt] = *(const short8*)&Bs[p][(wmh * 64 + nt * 16 + lr) * 32 + rdoff];
#pragma unroll
    for (int mt = 0; mt < 2; ++mt)
#pragma unroll
      for (int nt = 0; nt < 4; ++nt)
        acc[mt][nt] = __builtin_amdgcn_mfma_f32_16x16x32_bf16(
            af[mt], bfr[nt], acc[mt][nt], 0, 0, 0);
  };

#pragma unroll
  for (int it = 0; it < 8; ++it) {
    if (it + 2 < 8) loadH(it + 2, hs[it & 1]);  // into set just retired
    compute(it & 1, it);
    if (it + 1 < 8) {
      if (it + 2 < 8)
        asm volatile("s_waitcnt vmcnt(4)" ::: "memory");  // set (it+1) landed
      else
        asm volatile("s_waitcnt vmcnt(0)" ::: "memory");
      stageH(hs[(it + 1) & 1], (it + 1) & 1);
    }
    __syncthreads();
  }

  // epilogue: Gt = (acc + bias) * dis_m  (bf16)
  float dm[4];
#pragma unroll
  for (int nt = 0; nt < 4; ++nt)
    dm[nt] = dis[batch * 512 + mt0 + wmh * 64 + nt * 16 + lr];
#pragma unroll
  for (int mt = 0; mt < 2; ++mt) {
    const int ob = ot0 + wo * 32 + mt * 16 + q * 4;
    float bs4[4];
#pragma unroll
    for (int r = 0; r < 4; ++r) bs4[r] = bias[ob + r];
#pragma unroll
    for (int nt = 0; nt < 4; ++nt) {
      const int m = mt0 + wmh * 64 + nt * 16 + lr;
      ushort_t* dstp = Gt + ((size_t)batch * 256 + ob) * 512 + m;
#pragma unroll
      for (int r = 0; r < 4; ++r)
        dstp[(size_t)r * 512] = f2bf((acc[mt][nt][r] + bs4[r]) * dm[nt]);
    }
  }
}

// --- K3: out[b][n][o] = relu( (Ahat @ G)[n,o] * dis[b,n] * mask[b,n] ) ------
// tile 128(n) x 64(o), K=512; double-buffered single-barrier K-loop.
// grid 512, bid = yo*128 + batch*4 + xn  (Ahat-sharers land on one XCD)
__global__ __launch_bounds__(256) void k_gemm_out(
    const ushort_t* __restrict__ Abf,  // [32][512][512] (A + I)
    const ushort_t* __restrict__ Gt,   // [32][256][512]
    const float* __restrict__ dis,     // [32*512]
    const float* __restrict__ mask,    // [32*512]
    float* __restrict__ out) {         // [32][512][256]
  __shared__ ushort_t As[2][128 * 32];  // Ahat rows (n x k)
  __shared__ ushort_t Bs[2][64 * 32];   // Gt rows   (o x k)
  const int bid = blockIdx.x;
  const int yo = bid >> 7;      // o-tile 0..3
  const int rr = bid & 127;
  const int batch = rr >> 2;    // 0..31
  const int xn = rr & 3;        // n-tile 0..3
  const int nt0 = xn * 128, ot0 = yo * 64;
  const int tid = threadIdx.x, lane = tid & 63, wv = tid >> 6;
  const int wnh = wv & 1;   // n half (2 x 64)
  const int woh = wv >> 1;  // o half (2 x 32)
  const int lr = lane & 15, q = lane >> 4;
  const int rstage = lane >> 2, koff = (lane & 3) * 8;
  const ushort_t* Ab = Abf + (size_t)batch * 512 * 512;
  const ushort_t* Gb = Gt + (size_t)batch * 256 * 512;

  f32x4 acc[4][2];
#pragma unroll
  for (int i = 0; i < 4; ++i)
#pragma unroll
    for (int j = 0; j < 2; ++j) acc[i][j] = {0.f, 0.f, 0.f, 0.f};

  auto stage = [&](int k0, int p) {
#pragma unroll
    for (int j = 0; j < 2; ++j) {
      const int c = wv * 2 + j;
      load_lds16(Ab + (size_t)(nt0 + c * 16 + rstage) * 512 + k0 + koff,
                 &As[p][c * 512]);
    }
    load_lds16(Gb + (size_t)(ot0 + wv * 16 + rstage) * 512 + k0 + koff,
               &Bs[p][wv * 512]);
  };
  auto compute = [&](int p) {
    short8 af[4], bfr[2];
#pragma unroll
    for (int mt = 0; mt < 4; ++mt)
      af[mt] = *(const short8*)&As[p][(wnh * 64 + mt * 16 + lr) * 32 + q * 8];
#pragma unroll
    for (int nt = 0; nt < 2; ++nt)
      bfr[nt] = *(const short8*)&Bs[p][(woh * 32 + nt * 16 + lr) * 32 + q * 8];
#pragma unroll
    for (int mt = 0; mt < 4; ++mt)
#pragma unroll
      for (int nt = 0; nt < 2; ++nt)
        acc[mt][nt] = __builtin_amdgcn_mfma_f32_16x16x32_bf16(
            af[mt], bfr[nt], acc[mt][nt], 0, 0, 0);
  };

  stage(0, 0);
#pragma unroll
  for (int it = 0; it < 16; ++it) {
    __syncthreads();
    if (it + 1 < 16) stage((it + 1) * 32, (it + 1) & 1);
    compute(it & 1);
  }

#pragma unroll
  for (int mt = 0; mt < 4; ++mt) {
    const int nb = nt0 + wnh * 64 + mt * 16 + q * 4;
    float sc[4];
#pragma unroll
    for (int r = 0; r < 4; ++r) {
      const int gn = batch * 512 + nb + r;
      sc[r] = dis[gn] * mask[gn];
    }
#pragma unroll
    for (int nt = 0; nt < 2; ++nt) {
      const int o = ot0 + woh * 32 + nt * 16 + lr;
      float* dstp = out + ((size_t)(batch * 512 + nb)) * 256 + o;
#pragma unroll
      for (int r = 0; r < 4; ++r) {
        float v = acc[mt][nt][r] * sc[r];
        dstp[(size_t)r * 256] = v > 0.0f ? v : 0.0f;
      }
    }
  }
}

extern "C" void kernel_launch(void* const* d_in, const int* in_sizes, int n_in,
                              void* d_out, int out_size, void* d_ws,
                              size_t ws_size, hipStream_t stream) {
  const float* H = (const float*)d_in[0];     // [32][512][256]
  const float* A = (const float*)d_in[1];     // [32][512][512]
  const float* mask = (const float*)d_in[2];  // [32][512]
  const float* W = (const float*)d_in[3];     // [256][256]
  const float* b = (const float*)d_in[4];     // [256]
  float* out = (float*)d_out;                 // [32][512][256]

  char* ws = (char*)d_ws;
  ushort_t* Abf = (ushort_t*)ws;                   // 16 MiB (A + I, bf16)
  ushort_t* Gt = (ushort_t*)(ws + 16777216);       // 8 MiB  (dis_m-scaled)
  float* dis = (float*)(ws + 16777216 + 8388608);  // 64 KiB

  // 1) deg->dis, (A+I)->bf16   (A read once, fp32)
  k_prep<<<4096, 256, 0, stream>>>((const float4*)A, Abf, dis);
  // 2) Gt = dis * (W @ H^T + b)   (H,W read fp32 directly)
  k_gemm_gt<<<512, 256, 0, stream>>>((const float4*)H, (const float4*)W, b,
                                     dis, Gt);
  // 3) out = relu(mask * dis * (Ahat @ G))
  k_gemm_out<<<512, 256, 0, stream>>>(Abf, Gt, dis, mask, out);
}

// Round 5
// 115.934 us; speedup vs baseline: 1.0457x; 1.0030x over previous
//
#include <hip/hip_runtime.h>
#include <stdint.h>

typedef __attribute__((ext_vector_type(8))) short short8;
typedef __attribute__((ext_vector_type(4))) float f32x4;
typedef unsigned short ushort_t;

// fp32 -> bf16 round-to-nearest-even
__device__ __forceinline__ ushort_t f2bf(float f) {
  uint32_t u = __float_as_uint(f);
  u += 0x7fffu + ((u >> 16) & 1u);
  return (ushort_t)(u >> 16);
}

__device__ __forceinline__ uint2 pack4(float4 v) {
  return make_uint2((uint32_t)f2bf(v.x) | ((uint32_t)f2bf(v.y) << 16),
                    (uint32_t)f2bf(v.z) | ((uint32_t)f2bf(v.w) << 16));
}

// async global->LDS, 16B per lane; LDS dest = wave-uniform base + lane*16
__device__ __forceinline__ void load_lds16(const ushort_t* g, ushort_t* l) {
  __builtin_amdgcn_global_load_lds(
      (const __attribute__((address_space(1))) uint32_t*)g,
      (__attribute__((address_space(3))) uint32_t*)l, 16, 0, 0);
}

// --- K1: dis[row] = rsqrt(rowsum(A) + 1 + eps) ------------------------------
// Pure streaming read of A (33.5 MB) -> A is L3-resident for k_out.
__global__ __launch_bounds__(256) void k_dis(const float4* __restrict__ A4,
                                             float* __restrict__ dis) {
  const int tid = threadIdx.x, lane = tid & 63, wv = tid >> 6;
#pragma unroll
  for (int rr = 0; rr < 4; ++rr) {
    const int row = blockIdx.x * 16 + rr * 4 + wv;  // b*512 + n
    const float4* src = A4 + (size_t)row * 128;
    float s = 0.0f;
#pragma unroll
    for (int i = 0; i < 2; ++i) {
      float4 v = src[i * 64 + lane];
      s += (v.x + v.y) + (v.z + v.w);
    }
#pragma unroll
    for (int off = 32; off > 0; off >>= 1) s += __shfl_down(s, off, 64);
    if (lane == 0) dis[row] = rsqrtf(s + 1.0f + 1e-8f);  // +1 self-loop
  }
}

// --- K2: Gt[b][o][m] = (sum_i W[o,i]*H[b,m,i] + bias[o]) * dis[b,m] ---------
// o-tile 64 x m-tile 128, K=256 (8 steps of 32). W,H read fp32 directly:
// whole W o-tile converted once into 32 KB LDS; H reg-staged fp32->bf16,
// 2-deep double buffer. XOR 16B-slot swizzle on both LDS tiles.
// grid 512, bid = yo*128 + batch*4 + xm        (UNCHANGED: passed round 3)
__global__ __launch_bounds__(256) void k_gemm_gt(
    const float4* __restrict__ H4,   // [32*512][64]  fp32 rows
    const float4* __restrict__ W4,   // [256][64]     fp32 rows
    const float* __restrict__ bias,  // [256]
    const float* __restrict__ dis,   // [32*512]
    ushort_t* __restrict__ Gt) {     // [32][256][512] bf16
  __shared__ ushort_t Ws[64 * 256];     // whole W o-tile, bf16, 32 KB
  __shared__ ushort_t Bs[2][128 * 32];  // H k-step tiles, bf16, 2 x 8 KB
  const int bid = blockIdx.x, tid = threadIdx.x;
  const int yo = bid >> 7;    // o-tile 0..3
  const int rb = bid & 127;
  const int batch = rb >> 2;  // 0..31
  const int xm = rb & 3;      // m-tile 0..3
  const int ot0 = yo * 64, mt0 = xm * 128;
  const int lane = tid & 63, wv = tid >> 6;
  const int wo = wv & 1;    // o half (2 x 32)
  const int wmh = wv >> 1;  // m half (2 x 64)
  const int lr = lane & 15, q = lane >> 4;
  const float4* Hb4 = H4 + (size_t)batch * 512 * 64;

  f32x4 acc[2][4];
#pragma unroll
  for (int i = 0; i < 2; ++i)
#pragma unroll
    for (int j = 0; j < 4; ++j) acc[i][j] = {0.f, 0.f, 0.f, 0.f};

  // H staging lane map: 8 lanes x float4 per row segment
  const int hr = tid >> 3, hc = tid & 7;
  float4 hs[2][4];
  auto loadH = [&](int step, float4* hv) {
#pragma unroll
    for (int c = 0; c < 4; ++c)
      hv[c] = Hb4[(size_t)(mt0 + hr + 32 * c) * 64 + step * 8 + hc];
  };
  // store slot s holds data chunk s ^ ((row>>1)&3)  (16B slots, matches rdoff)
  auto stageH = [&](const float4* hv, int p) {
    const int d = hc >> 1, sub = hc & 1;
#pragma unroll
    for (int c = 0; c < 4; ++c) {
      const int r = hr + 32 * c;
      *(uint2*)&Bs[p][r * 32 + ((d ^ ((r >> 1) & 3)) << 3) + (sub << 2)] =
          pack4(hv[c]);
    }
  };

  loadH(0, hs[0]);
  loadH(1, hs[1]);
  // W o-tile fp32 -> bf16 LDS, 16B-slot XOR swizzle by (o&7)
#pragma unroll
  for (int i = 0; i < 16; ++i) {
    const int e4 = i * 256 + tid;
    const int o = e4 >> 6, k = (e4 & 63) * 4;
    *(uint2*)&Ws[o * 256 + (k ^ ((o & 7) << 3))] =
        pack4(W4[(size_t)ot0 * 64 + e4]);
  }
  asm volatile("s_waitcnt vmcnt(4)" ::: "memory");  // hs[0] landed (W drained)
  stageH(hs[0], 0);
  __syncthreads();  // Ws + Bs[0] visible

  auto compute = [&](int p, int it) {
    short8 af[2], bfr[4];
#pragma unroll
    for (int mt = 0; mt < 2; ++mt) {
      const int ro = wo * 32 + mt * 16 + lr;
      af[mt] = *(const short8*)&Ws[ro * 256 +
                                   ((it * 32 + q * 8) ^ ((ro & 7) << 3))];
    }
    const int rdoff = (q ^ ((lane >> 1) & 3)) * 8;
#pragma unroll
    for (int nt = 0; nt < 4; ++nt)
      bfr[nt] = *(const short8*)&Bs[p][(wmh * 64 + nt * 16 + lr) * 32 + rdoff];
#pragma unroll
    for (int mt = 0; mt < 2; ++mt)
#pragma unroll
      for (int nt = 0; nt < 4; ++nt)
        acc[mt][nt] = __builtin_amdgcn_mfma_f32_16x16x32_bf16(
            af[mt], bfr[nt], acc[mt][nt], 0, 0, 0);
  };

#pragma unroll
  for (int it = 0; it < 8; ++it) {
    if (it + 2 < 8) loadH(it + 2, hs[it & 1]);  // into set just retired
    compute(it & 1, it);
    if (it + 1 < 8) {
      if (it + 2 < 8)
        asm volatile("s_waitcnt vmcnt(4)" ::: "memory");  // set (it+1) landed
      else
        asm volatile("s_waitcnt vmcnt(0)" ::: "memory");
      stageH(hs[(it + 1) & 1], (it + 1) & 1);
    }
    __syncthreads();
  }

  // epilogue: Gt = (acc + bias) * dis_m  (bf16)
  float dm[4];
#pragma unroll
  for (int nt = 0; nt < 4; ++nt)
    dm[nt] = dis[batch * 512 + mt0 + wmh * 64 + nt * 16 + lr];
#pragma unroll
  for (int mt = 0; mt < 2; ++mt) {
    const int ob = ot0 + wo * 32 + mt * 16 + q * 4;
    float bs4[4];
#pragma unroll
    for (int r = 0; r < 4; ++r) bs4[r] = bias[ob + r];
#pragma unroll
    for (int nt = 0; nt < 4; ++nt) {
      const int m = mt0 + wmh * 64 + nt * 16 + lr;
      ushort_t* dstp = Gt + ((size_t)batch * 256 + ob) * 512 + m;
#pragma unroll
      for (int r = 0; r < 4; ++r)
        dstp[(size_t)r * 512] = f2bf((acc[mt][nt][r] + bs4[r]) * dm[nt]);
    }
  }
}

// --- K3: out[b][n][o] = relu( (Ahat @ G)[n,o] * dis[b,n] * mask[b,n] ) ------
// tile 128(n) x 128(o), K=512 (16 steps of 32), 512 threads (8 waves: 2n x 4o).
// A-operand read fp32 DIRECTLY (L3-hot from k_dis), +I folded at the bf16
// conversion -> no Abf materialization. Gt via global_load_lds, 2-buffer.
// Loop shape = proven k_gemm_gt pattern: loads at top, __syncthreads drain
// each iteration; NO manual waitcnt (round-4's counted-vmcnt raced on the
// heterogeneous {loadG, loadA} group order).
// grid 256, bid = yo*128 + batch*4 + xn (A-sharers 128 apart -> same XCD).
__global__ __launch_bounds__(512) void k_out(
    const float4* __restrict__ A4,    // [32*512][128] fp32 rows
    const ushort_t* __restrict__ Gt,  // [32][256][512] bf16 (dis_m-scaled)
    const float* __restrict__ dis,    // [32*512]
    const float* __restrict__ mask,   // [32*512]
    float* __restrict__ out) {        // [32][512][256]
  __shared__ ushort_t As[2][128 * 32];  // Ahat rows (n x k), swizzled slots
  __shared__ ushort_t Bs[2][128 * 32];  // Gt rows   (o x k), linear
  const int bid = blockIdx.x;
  const int yo = bid >> 7;    // o-tile 0..1 (128 each)
  const int rb = bid & 127;
  const int batch = rb >> 2;  // 0..31
  const int xn = rb & 3;      // n-tile 0..3
  const int nt0 = xn * 128, ot0 = yo * 128;
  const int tid = threadIdx.x, lane = tid & 63, wv = tid >> 6;  // 8 waves
  const int wn = wv & 1;   // n half (2 x 64)
  const int wq = wv >> 1;  // o quarter (4 x 32)
  const int lr = lane & 15, q = lane >> 4;
  const int rstage = lane >> 2, koff = (lane & 3) * 8;
  const float4* Ab4 = A4 + (size_t)(batch * 512 + nt0) * 128;
  const ushort_t* Gb = Gt + ((size_t)batch * 256 + ot0) * 512;

  f32x4 acc[4][2];
#pragma unroll
  for (int i = 0; i < 4; ++i)
#pragma unroll
    for (int j = 0; j < 2; ++j) acc[i][j] = {0.f, 0.f, 0.f, 0.f};

  // A staging: 512 thr = 64 rows x 8 float4-cols; 2 row-groups per thread
  const int hr = tid >> 3, hc = tid & 7;
  float4 hs[2][2];
  auto loadA = [&](int step, float4* hv) {
#pragma unroll
    for (int c = 0; c < 2; ++c)
      hv[c] = Ab4[(size_t)(hr + 64 * c) * 128 + step * 8 + hc];
  };
  // fold +I at conversion; store slot d^((r>>1)&3) (matches rdoff read)
  auto stageA = [&](const float4* hv, int p, int step) {
    const int d = hc >> 1, sub = hc & 1;
    const int m0 = step * 32 + hc * 4;
#pragma unroll
    for (int c = 0; c < 2; ++c) {
      const int r = hr + 64 * c;
      const int ng = nt0 + r;  // n within batch
      float4 v = hv[c];
      v.x += (float)(m0 == ng);
      v.y += (float)(m0 + 1 == ng);
      v.z += (float)(m0 + 2 == ng);
      v.w += (float)(m0 + 3 == ng);
      *(uint2*)&As[p][r * 32 + ((d ^ ((r >> 1) & 3)) << 3) + (sub << 2)] =
          pack4(v);
    }
  };
  // Gt: 8 waves x 16 rows, linear layout (lane l -> row wv*16+l/4, col (l&3)*8)
  auto loadG = [&](int step, int p) {
    load_lds16(Gb + (size_t)(wv * 16 + rstage) * 512 + step * 32 + koff,
               &Bs[p][wv * 512]);
  };

  auto compute = [&](int p) {
    short8 af[4], bfr[2];
    const int rdoff = (q ^ ((lane >> 1) & 3)) * 8;
#pragma unroll
    for (int mt = 0; mt < 4; ++mt)
      af[mt] = *(const short8*)&As[p][(wn * 64 + mt * 16 + lr) * 32 + rdoff];
#pragma unroll
    for (int nt = 0; nt < 2; ++nt)
      bfr[nt] = *(const short8*)&Bs[p][(wq * 32 + nt * 16 + lr) * 32 + q * 8];
#pragma unroll
    for (int mt = 0; mt < 4; ++mt)
#pragma unroll
      for (int nt = 0; nt < 2; ++nt)
        acc[mt][nt] = __builtin_amdgcn_mfma_f32_16x16x32_bf16(
            af[mt], bfr[nt], acc[mt][nt], 0, 0, 0);
  };

  // prologue: A0,A1 -> regs; G0 -> LDS; stage A0 (compiler waits reg deps);
  // __syncthreads drains vmcnt (G0 landed) + publishes As[0].
  loadA(0, hs[0]);
  loadA(1, hs[1]);
  loadG(0, 0);
  stageA(hs[0], 0, 0);
  __syncthreads();

#pragma unroll
  for (int it = 0; it < 16; ++it) {
    if (it + 1 < 16) loadG(it + 1, (it + 1) & 1);
    if (it + 2 < 16) loadA(it + 2, hs[it & 1]);
    compute(it & 1);
    // A(it+1) regs were drained by the previous __syncthreads (vmcnt(0))
    if (it + 1 < 16) stageA(hs[(it + 1) & 1], (it + 1) & 1, it + 1);
    __syncthreads();  // drains loadG/loadA, publishes As/Bs for it+1
  }

  // epilogue: out = relu(acc * dis_n * mask_n)
#pragma unroll
  for (int mt = 0; mt < 4; ++mt) {
    const int nb = nt0 + wn * 64 + mt * 16 + q * 4;
    float sc[4];
#pragma unroll
    for (int r = 0; r < 4; ++r) {
      const int gn = batch * 512 + nb + r;
      sc[r] = dis[gn] * mask[gn];
    }
#pragma unroll
    for (int nt = 0; nt < 2; ++nt) {
      const int o = ot0 + wq * 32 + nt * 16 + lr;
      float* dstp = out + (size_t)(batch * 512 + nb) * 256 + o;
#pragma unroll
      for (int r = 0; r < 4; ++r) {
        float v = acc[mt][nt][r] * sc[r];
        dstp[(size_t)r * 256] = v > 0.0f ? v : 0.0f;
      }
    }
  }
}

extern "C" void kernel_launch(void* const* d_in, const int* in_sizes, int n_in,
                              void* d_out, int out_size, void* d_ws,
                              size_t ws_size, hipStream_t stream) {
  const float* H = (const float*)d_in[0];     // [32][512][256]
  const float* A = (const float*)d_in[1];     // [32][512][512]
  const float* mask = (const float*)d_in[2];  // [32][512]
  const float* W = (const float*)d_in[3];     // [256][256]
  const float* b = (const float*)d_in[4];     // [256]
  float* out = (float*)d_out;                 // [32][512][256]

  char* ws = (char*)d_ws;
  ushort_t* Gt = (ushort_t*)ws;         // 8 MiB (dis_m-scaled, bf16)
  float* dis = (float*)(ws + 8388608);  // 64 KiB

  // 1) dis = rsqrt(rowsum(A)+1+eps)   (A -> L3)
  k_dis<<<1024, 256, 0, stream>>>((const float4*)A, dis);
  // 2) Gt = dis_m * (W @ H^T + b)     (H,W fp32 direct)
  k_gemm_gt<<<512, 256, 0, stream>>>((const float4*)H, (const float4*)W, b,
                                     dis, Gt);
  // 3) out = relu(mask * dis_n * (Ahat @ G))   (A fp32 from L3, +I on the fly)
  k_out<<<256, 512, 0, stream>>>((const float4*)A, Gt, dis, mask, out);
}